// Round 22
// baseline (52.253 us; speedup 1.0000x reference)
//
#include <hip/hip_runtime.h>
#include <hip/hip_bf16.h>

// SelfAttention: B=4, S=4096, Din=768, Dout=64.
// R22: attn on 32x32x16 MFMA — 2x FLOP per ds_read_b128 (attn's binder is
//  LDS instruction issue: ~1730/2025 cyc). Swapped QK (S^T = K·Q^T) makes the
//  32x32 D layout (kv=(reg&3)+8(reg>>2)+4h, q=lane&31) match PV's B layout
//  via ONLY lane-half exchanges = v_permlane32_swap_b32 (VALU pipe, not
//  ds_bpermute — R15's mistake). P fully in-register: no pbuf, no drain.
//  8 waves = 2 q-strips(32q) x 4 kv-parities(32kv), KVT=128, 4-buf 2-deep
//  staging vmcnt(8) (R16 lesson: cover staging latency when compute shrinks).
//  Element-chase verified: swap(pk0,pk2),swap(pk1,pk3) -> B(ks=0) in place;
//  swap(pk4,pk6),swap(pk5,pk7) -> B(ks=1).
//  proj/convert byte-exact R21 (validated 51.6us state).

typedef __attribute__((ext_vector_type(8)))  __bf16 bf16x8;
typedef __attribute__((ext_vector_type(4)))  __bf16 bf16x4;
typedef __attribute__((ext_vector_type(4)))  float  f32x4;
typedef __attribute__((ext_vector_type(2)))  float  f32x2;
typedef __attribute__((ext_vector_type(16))) float  f32x16;

constexpr int BATCH = 4;
constexpr int SEQ   = 4096;
constexpr int DIN   = 768;
constexpr int NTOT  = 192;
constexpr int MROWS = BATCH * SEQ;  // 16384
constexpr int KVT   = 128;          // kv tile (128 rows x 128B K, 64 x 256B V)

__device__ __forceinline__ f32x4 mfma16(bf16x8 a, bf16x8 b, f32x4 c) {
    return __builtin_amdgcn_mfma_f32_16x16x32_bf16(a, b, c, 0, 0, 0);
}
__device__ __forceinline__ f32x16 mfma32(bf16x8 a, bf16x8 b, f32x16 c) {
    return __builtin_amdgcn_mfma_f32_32x32x16_bf16(a, b, c, 0, 0, 0);
}

__device__ __forceinline__ void gload_lds16(const void* g, void* l) {
    __builtin_amdgcn_global_load_lds(
        (const __attribute__((address_space(1))) void*)g,
        (__attribute__((address_space(3))) void*)l, 16, 0, 0);
}

// pack two floats into one dword of bf16 pairs (lo<-f0, hi<-f1); compiler
// conversions (validated in R15).
__device__ __forceinline__ unsigned pack_bf16(float f0, float f1) {
    unsigned short u0 = __builtin_bit_cast(unsigned short, (__bf16)f0);
    unsigned short u1 = __builtin_bit_cast(unsigned short, (__bf16)f1);
    return (unsigned)u0 | ((unsigned)u1 << 16);
}

// ---------------- k0: pack Wq|Wk|Wv -> bf16 [192][768]; Wq pre-scaled by
// 0.125*log2(e) so attention scores come out in exp2 domain.
__global__ __launch_bounds__(256) void convert_w(
        const float* __restrict__ Wq, const float* __restrict__ Wk,
        const float* __restrict__ Wv, __bf16* __restrict__ wb) {
    int i = blockIdx.x * 256 + threadIdx.x;
    if (i >= NTOT * DIN) return;
    int n = i / DIN;
    const float* src = (n < 64) ? Wq : (n < 128) ? Wk : Wv;
    float scale = (n < 64) ? 0.125f * 1.44269504f : 1.0f;
    wb[i] = (__bf16)(src[(n & 63) * DIN + (i % DIN)] * scale);
}

// ---------------- k1: q,k,v = x @ W^T  (M=16384, N=192, K=768)  [= R21]
__global__ __launch_bounds__(1024, 4) void qkv_proj(
        const float* __restrict__ x, const __bf16* __restrict__ wb,
        __bf16* __restrict__ q, __bf16* __restrict__ k, __bf16* __restrict__ vT) {
    const int tid  = threadIdx.x;
    const int wave = tid >> 6, lane = tid & 63;
    const int strip = wave & 3, nh = wave >> 2;
    const int lr = lane & 15;
    const int g  = lane >> 4;
    const int rx = (lr & 7) << 4;

    __shared__ __align__(16) char wbuf[3][NTOT * 128];   // 72 KiB
    __shared__ __align__(16) char xbuf[4][64 * 256];     // 64 KiB

    const int  srow = lane >> 3;
    const int  ssw  = ((lane & 7) << 4) ^ ((srow & 7) << 4);
    const int  xs4  = lane >> 4;
    const char* wbb = (const char*)wb;
    const char* xbb = (const char*)x;
    const int  xrow0 = blockIdx.x * 64;

    const int wi0 = wave;
    const int wi1 = (wave + 16) % 24;
    const int xrow = wave * 4 + xs4;
    const int sswx = ((lane & 15) ^ (xrow & 15)) << 4;

    auto stage_w = [&](int buf, int kt) {
#pragma unroll
        for (int s = 0; s < 2; ++s) {
            const int wi = (s == 0) ? wi0 : wi1;
            gload_lds16(wbb + (size_t)(wi * 8 + srow) * (DIN * 2) + kt * 128 + ssw,
                        &wbuf[buf][wi * 8 * 128]);
        }
    };
    auto stage_x = [&](int buf, int kt) {
        gload_lds16(xbb + (size_t)(xrow0 + xrow) * (DIN * 4) + kt * 256 + sswx,
                    &xbuf[buf][wave * 4 * 256]);
    };

    f32x4 acc[3];
#pragma unroll
    for (int t = 0; t < 3; ++t) acc[t] = f32x4{0.f, 0.f, 0.f, 0.f};

    stage_w(0, 0);
    stage_x(0, 0);
    stage_x(1, 1);
    asm volatile("s_waitcnt vmcnt(1) lgkmcnt(0)" ::: "memory");
    __builtin_amdgcn_s_barrier();

    constexpr int NT = DIN / 64;   // 12
    for (int kt = 0; kt < NT; ++kt) {
        stage_w((kt + 1) % 3, (kt + 1) % NT);
        stage_x((kt + 2) & 3, (kt + 2) % NT);
        asm volatile("s_waitcnt vmcnt(4) lgkmcnt(0)" ::: "memory");
        __builtin_amdgcn_s_barrier();

        const char* wbc = wbuf[kt % 3];
        const char* xbc = xbuf[kt & 3];
#pragma unroll
        for (int ks = 0; ks < 2; ++ks) {
            const char* xrp = xbc + (strip * 16 + lr) * 256;
            f32x4 xa = *(const f32x4*)(xrp + ((ks * 128 + g * 32)      ^ (lr << 4)));
            f32x4 xb = *(const f32x4*)(xrp + ((ks * 128 + g * 32 + 16) ^ (lr << 4)));
            bf16x8 af;
            af[0] = (__bf16)xa[0]; af[1] = (__bf16)xa[1]; af[2] = (__bf16)xa[2]; af[3] = (__bf16)xa[3];
            af[4] = (__bf16)xb[0]; af[5] = (__bf16)xb[1]; af[6] = (__bf16)xb[2]; af[7] = (__bf16)xb[3];
#pragma unroll
            for (int t = 0; t < 3; ++t) {
                const int nr = (nh * 3 + t) * 16 + lr;
                bf16x8 bf = *(const bf16x8*)(wbc + nr * 128 +
                                             ((ks * 64 + g * 16) ^ rx));
                acc[t] = mfma16(af, bf, acc[t]);
            }
        }
    }

    const int orow_l = strip * 16 + g * 4;
#pragma unroll
    for (int t = 0; t < 3; ++t) {
        const int n = (nh * 3 + t) * 16 + lr;
        if (n < 128) {
#pragma unroll
            for (int r = 0; r < 4; ++r) {
                const int m = blockIdx.x * 64 + orow_l + r;
                __bf16 hv = (__bf16)acc[t][r];
                if (n < 64) q[(size_t)m * 64 + n] = hv;
                else        k[(size_t)m * 64 + (n - 64)] = hv;
            }
        }
    }

    asm volatile("s_waitcnt vmcnt(0) lgkmcnt(0)" ::: "memory");
    __syncthreads();
    char* vt = &xbuf[0][0];
#pragma unroll
    for (int t = 0; t < 3; ++t) {
        const int n = (nh * 3 + t) * 16 + lr;
        if (n >= 128) {
            const int nn  = n - 128;
            const int key = (nn & 7) << 4;
#pragma unroll
            for (int r = 0; r < 4; ++r) {
                const int mm = orow_l + r;
                *(__bf16*)(vt + nn * 128 + ((mm * 2) ^ key)) = (__bf16)acc[t][r];
            }
        }
    }
    __syncthreads();
    if (wave < 8) {
        const int nn = wave * 8 + (lane >> 3);
        const int s  = lane & 7;
        const int sl = s ^ (nn & 7);
        bf16x8 vv = *(const bf16x8*)(vt + nn * 128 + s * 16);
        __bf16* dst = vT + (size_t)(blockIdx.x >> 6) * 64 * SEQ
                    + (size_t)nn * SEQ + (blockIdx.x & 63) * 64 + sl * 8;
        *(bf16x8*)dst = vv;
    }
}

// ---------------- k2: flash attention on 32x32 MFMA, in-register P.
// grid = (SEQ/64, BATCH) = 256 blocks, 512 threads = 8 waves
// (strip = wave&1 -> 32 q rows; par = wave>>1 -> 32 kv rows of each tile).
__global__ __launch_bounds__(512, 2) void attn(
        const __bf16* __restrict__ q, const __bf16* __restrict__ k,
        const __bf16* __restrict__ vT, float* __restrict__ out) {
    const int tid  = threadIdx.x;
    const int wave = tid >> 6, lane = tid & 63;
    const int strip = wave & 1, par = wave >> 1;   // 2 strips x 4 parities
    const int b  = blockIdx.y;
    const int q0 = blockIdx.x * 64 + strip * 32;
    const int la = lane & 31;          // q (QK-B / PV cols), kv row (QK-A), d (PV-A)
    const int h  = lane >> 5;          // lane half

    const __bf16* qp = q  + (size_t)b * SEQ * 64;
    const __bf16* kp = k  + (size_t)b * SEQ * 64;
    const __bf16* vp = vT + (size_t)b * 64 * SEQ;

    __shared__ __align__(16) char kbuf[4][KVT * 128];   // 64 KiB
    __shared__ __align__(16) char vbuf[4][64 * 256];    // 64 KiB
    __shared__ float lbuf[4][2][32];                    //  1 KiB

    // staging: 4 ops/wave (2 K ops of 8 rows, 2 V ops of 4 rows)
    const int srow8 = lane >> 3;
    const int sswK  = ((lane & 7) << 4) ^ (srow8 << 4);
    const int vr4   = lane >> 4;

    auto stage = [&](int buf, int kv0) {
#pragma unroll
        for (int s = 0; s < 2; ++s) {
            const int krow = wave * 16 + s * 8 + srow8;
            gload_lds16((const char*)kp + (size_t)(kv0 + krow) * 128 + sswK,
                        &kbuf[buf][(wave * 16 + s * 8) * 128]);
            const int vrow = wave * 8 + s * 4 + vr4;
            const int sswV = ((lane & 15) ^ (vrow & 7)) << 4;
            gload_lds16((const char*)vp + (size_t)vrow * (SEQ * 2) +
                            (size_t)kv0 * 2 + sswV,
                        &vbuf[buf][(wave * 8 + s * 4) * 256]);
        }
    };

    // Q fragments (loop-invariant B-operands): bq[ki] = Q[q0+la][16ki+8h ..+8]
    bf16x8 bq[4];
#pragma unroll
    for (int ki = 0; ki < 4; ++ki)
        bq[ki] = *(const bf16x8*)(qp + (size_t)(q0 + la) * 64 + 16 * ki + 8 * h);

    f32x16 acc[2];
#pragma unroll
    for (int t = 0; t < 2; ++t)
#pragma unroll
        for (int r = 0; r < 16; ++r) acc[t][r] = 0.f;
    float l_run = 0.f;

    stage(0, 0);
    stage(1, KVT);

    constexpr int NT = SEQ / KVT;   // 32
    const int kx = (lane & 7) << 4;
    for (int it = 0; it < NT; ++it) {
        stage((it + 2) & 3, ((it + 2) % NT) * KVT);
        // completes stage(it) (issued 2 iters ago); leaves it+1,it+2 in flight
        asm volatile("s_waitcnt vmcnt(8) lgkmcnt(0)" ::: "memory");
        __builtin_amdgcn_s_barrier();
        const int cur = it & 3;

        // ---- S^T = K Q^T (32kv x 32q, exp2 domain), K=64 as 4 x K16 steps
        f32x16 s;
#pragma unroll
        for (int r = 0; r < 16; ++r) s[r] = 0.f;
        const char* krp = &kbuf[cur][(par * 32 + la) * 128];
#pragma unroll
        for (int ki = 0; ki < 4; ++ki) {
            bf16x8 kf = *(const bf16x8*)(krp + ((32 * ki + 16 * h) ^ kx));
            s = mfma32(kf, bq[ki], s);
        }

        // ---- softmax (max-free): p = exp2(s); pack pairs; accumulate l.
        // s[r] = S^T[kv = (r&3)+8*(r>>2)+4h][q=la]
        unsigned pk[8];
        float l_add = 0.f;
#pragma unroll
        for (int j = 0; j < 8; ++j) {
            float p0 = __builtin_amdgcn_exp2f(s[2 * j]);
            float p1 = __builtin_amdgcn_exp2f(s[2 * j + 1]);
            l_add += p0 + p1;
            pk[j] = pack_bf16(p0, p1);
        }
        l_run += l_add;

        // ---- lane-half exchange -> PV B-fragments, in place (VALU pipe)
        asm("v_permlane32_swap_b32 %0, %1" : "+v"(pk[0]), "+v"(pk[2]));
        asm("v_permlane32_swap_b32 %0, %1" : "+v"(pk[1]), "+v"(pk[3]));
        asm("v_permlane32_swap_b32 %0, %1" : "+v"(pk[4]), "+v"(pk[6]));
        asm("v_permlane32_swap_b32 %0, %1" : "+v"(pk[5]), "+v"(pk[7]));
        union { unsigned u[4]; bf16x8 v; } B0, B1;
        B0.u[0] = pk[0]; B0.u[1] = pk[1]; B0.u[2] = pk[2]; B0.u[3] = pk[3];
        B1.u[0] = pk[4]; B1.u[1] = pk[5]; B1.u[2] = pk[6]; B1.u[3] = pk[7];

        // ---- O^T += V^T P (2 d-tiles x 2 K16 steps)
#pragma unroll
        for (int t = 0; t < 2; ++t) {
            const char* vrp = &vbuf[cur][(32 * t + la) * 256];
#pragma unroll
            for (int ks = 0; ks < 2; ++ks) {
                bf16x8 vf = *(const bf16x8*)(vrp +
                                ((par * 64 + 32 * ks + 16 * h) ^ kx));
                acc[t] = mfma32(vf, ks ? B1.v : B0.v, acc[t]);
            }
        }
    }

    // ---- epilogue: l half-merge, cross-parity merge via dead kbuf, store.
    l_run += __shfl_xor(l_run, 32);
    asm volatile("s_waitcnt vmcnt(0) lgkmcnt(0)" ::: "memory");
    __syncthreads();   // wrap prefetch drained; kbuf/vbuf reusable

    if (lane < 32) lbuf[par][strip][la] = l_run;

    const int rxq = (la & 7) << 3;   // f32x2 XOR key on q
    if (par > 0) {
        char* Rb = &kbuf[0][0] + (size_t)(((par - 1) * 2 + strip) * 8192);
#pragma unroll
        for (int t = 0; t < 2; ++t)
#pragma unroll
            for (int j = 0; j < 8; ++j) {
                const int d = 32 * t + ((2 * j) & 3) + 8 * (j >> 1) + 4 * h;
                f32x2 v2;
                v2[0] = acc[t][2 * j];
                v2[1] = acc[t][2 * j + 1];
                *(f32x2*)(Rb + la * 256 + ((d * 4) ^ rxq)) = v2;
            }
    }
    __syncthreads();
    if (par == 0) {
#pragma unroll
        for (int pi = 0; pi < 3; ++pi) {
            const char* Rb = &kbuf[0][0] + (size_t)((pi * 2 + strip) * 8192);
#pragma unroll
            for (int t = 0; t < 2; ++t)
#pragma unroll
                for (int j = 0; j < 8; ++j) {
                    const int d = 32 * t + ((2 * j) & 3) + 8 * (j >> 1) + 4 * h;
                    f32x2 v2 = *(const f32x2*)(Rb + la * 256 + ((d * 4) ^ rxq));
                    acc[t][2 * j]     += v2[0];
                    acc[t][2 * j + 1] += v2[1];
                }
        }
        float L = lbuf[0][strip][la] + lbuf[1][strip][la] +
                  lbuf[2][strip][la] + lbuf[3][strip][la];
        float inv = 1.f / L;
        float* ob = out + ((size_t)b * SEQ + q0 + la) * 64;
#pragma unroll
        for (int t = 0; t < 2; ++t)
#pragma unroll
            for (int qd = 0; qd < 4; ++qd) {
                const int d0 = 32 * t + 8 * qd + 4 * h;
                f32x4 v4;
#pragma unroll
                for (int i = 0; i < 4; ++i) v4[i] = acc[t][4 * qd + i] * inv;
                *(f32x4*)(ob + d0) = v4;
            }
    }
}

extern "C" void kernel_launch(void* const* d_in, const int* in_sizes, int n_in,
                              void* d_out, int out_size, void* d_ws, size_t ws_size,
                              hipStream_t stream) {
    const float* x  = (const float*)d_in[0];
    const float* Wq = (const float*)d_in[1];
    const float* Wk = (const float*)d_in[2];
    const float* Wv = (const float*)d_in[3];
    float* out = (float*)d_out;

    char* ws = (char*)d_ws;
    __bf16* wb = (__bf16*)(ws);
    __bf16* qb = (__bf16*)(ws + 294912);
    __bf16* kb = (__bf16*)(ws + 294912 + 2097152);
    __bf16* vT = (__bf16*)(ws + 294912 + 2u * 2097152);

    convert_w<<<dim3((NTOT * DIN + 255) / 256), dim3(256), 0, stream>>>(Wq, Wk, Wv, wb);
    qkv_proj<<<dim3(MROWS / 64), dim3(1024), 0, stream>>>(x, wb, qb, kb, vT);
    attn<<<dim3(SEQ / 64, BATCH), dim3(512), 0, stream>>>(qb, kb, vT, out);
}

// Round 23
// 51.586 us; speedup vs baseline: 1.0129x; 1.0129x over previous
//
#include <hip/hip_runtime.h>
#include <hip/hip_bf16.h>

// SelfAttention: B=4, S=4096, Din=768, Dout=64.
// R23 = byte-exact revert to R21/R19 (best validated: 51.58-51.65us, x2 repro).
//  Final state. R22's 32x32 attn was numerically perfect but neutral (52.25):
//  the 2.25x LDS-instr cut was repaid by halved occupancy — falsifying the
//  fifth and last attn structural theory. attn is invariant at ~2000cyc/tile
//  across wave count, MFMA shape, P-path, staging depth, XCD mapping.
//  Session summary: 192us (R1) -> 51.6us via LDS-staged K/V (R7), kv-parallel
//  waves (R8/R12), counted-vmcnt triple-buffer (R10), 16-wave proj + mixed-
//  depth staging (R14/R18), vT LDS-transpose epilogue (R19). Fusion (R20)
//  and 5 attn restructures falsified with mechanisms documented.

typedef __attribute__((ext_vector_type(8))) __bf16 bf16x8;
typedef __attribute__((ext_vector_type(4))) __bf16 bf16x4;
typedef __attribute__((ext_vector_type(4))) float  f32x4;

constexpr int BATCH = 4;
constexpr int SEQ   = 4096;
constexpr int DIN   = 768;
constexpr int NTOT  = 192;
constexpr int MROWS = BATCH * SEQ;  // 16384
constexpr int KVT   = 128;          // kv tile (128 rows x 128B K, 64 x 256B V)

__device__ __forceinline__ f32x4 mfma16(bf16x8 a, bf16x8 b, f32x4 c) {
    return __builtin_amdgcn_mfma_f32_16x16x32_bf16(a, b, c, 0, 0, 0);
}

__device__ __forceinline__ void gload_lds16(const void* g, void* l) {
    __builtin_amdgcn_global_load_lds(
        (const __attribute__((address_space(1))) void*)g,
        (__attribute__((address_space(3))) void*)l, 16, 0, 0);
}

// ---------------- k0: pack Wq|Wk|Wv -> bf16 [192][768]; Wq pre-scaled by
// 0.125*log2(e) so attention scores come out in exp2 domain.
__global__ __launch_bounds__(256) void convert_w(
        const float* __restrict__ Wq, const float* __restrict__ Wk,
        const float* __restrict__ Wv, __bf16* __restrict__ wb) {
    int i = blockIdx.x * 256 + threadIdx.x;
    if (i >= NTOT * DIN) return;
    int n = i / DIN;
    const float* src = (n < 64) ? Wq : (n < 128) ? Wk : Wv;
    float scale = (n < 64) ? 0.125f * 1.44269504f : 1.0f;
    wb[i] = (__bf16)(src[(n & 63) * DIN + (i % DIN)] * scale);
}

// ---------------- k1: q,k,v = x @ W^T  (M=16384, N=192, K=768)
// grid = 256 blocks of 64 rows; 16 waves = 4 row-strips x 4 n-quarters
// (3 n-tiles each). wb: 3 bufs staged 1 ahead; x: 4 bufs staged 2 ahead.
// Per-wave per-iter staging = 2 wb + 1 x ops -> steady vmcnt(4).
__global__ __launch_bounds__(1024, 4) void qkv_proj(
        const float* __restrict__ x, const __bf16* __restrict__ wb,
        __bf16* __restrict__ q, __bf16* __restrict__ k, __bf16* __restrict__ vT) {
    const int tid  = threadIdx.x;
    const int wave = tid >> 6, lane = tid & 63;
    const int strip = wave & 3, nh = wave >> 2;   // 4 strips x 4 n-quarters
    const int lr = lane & 15;
    const int g  = lane >> 4;
    const int rx = (lr & 7) << 4;

    __shared__ __align__(16) char wbuf[3][NTOT * 128];   // 72 KiB
    __shared__ __align__(16) char xbuf[4][64 * 256];     // 64 KiB

    const int  srow = lane >> 3;                          // wb: 8 rows/instr
    const int  ssw  = ((lane & 7) << 4) ^ ((srow & 7) << 4);
    const int  xs4  = lane >> 4;                          // x: 4 rows/instr
    const char* wbb = (const char*)wb;
    const char* xbb = (const char*)x;
    const int  xrow0 = blockIdx.x * 64;

    // wb instr assignment: wave w covers instrs w and (w+16)%24 (waves
    // 8..15's second instr duplicates rows 0..63 — identical bytes, benign).
    const int wi0 = wave;
    const int wi1 = (wave + 16) % 24;
    // x instr assignment: wave w covers rows [w*4, w*4+4) (4 rows of 256B).
    const int xrow = wave * 4 + xs4;
    const int sswx = ((lane & 15) ^ (xrow & 15)) << 4;

    auto stage_w = [&](int buf, int kt) {
#pragma unroll
        for (int s = 0; s < 2; ++s) {
            const int wi = (s == 0) ? wi0 : wi1;
            gload_lds16(wbb + (size_t)(wi * 8 + srow) * (DIN * 2) + kt * 128 + ssw,
                        &wbuf[buf][wi * 8 * 128]);
        }
    };
    auto stage_x = [&](int buf, int kt) {
        gload_lds16(xbb + (size_t)(xrow0 + xrow) * (DIN * 4) + kt * 256 + sswx,
                    &xbuf[buf][wave * 4 * 256]);
    };

    f32x4 acc[3];
#pragma unroll
    for (int t = 0; t < 3; ++t) acc[t] = f32x4{0.f, 0.f, 0.f, 0.f};

    stage_w(0, 0);
    stage_x(0, 0);
    stage_x(1, 1);
    asm volatile("s_waitcnt vmcnt(1) lgkmcnt(0)" ::: "memory");  // W0,X0 done
    __builtin_amdgcn_s_barrier();

    constexpr int NT = DIN / 64;   // 12
    for (int kt = 0; kt < NT; ++kt) {
        stage_w((kt + 1) % 3, (kt + 1) % NT);             // wrap: count const
        stage_x((kt + 2) & 3, (kt + 2) % NT);
        asm volatile("s_waitcnt vmcnt(4) lgkmcnt(0)" ::: "memory");
        __builtin_amdgcn_s_barrier();

        const char* wbc = wbuf[kt % 3];
        const char* xbc = xbuf[kt & 3];
#pragma unroll
        for (int ks = 0; ks < 2; ++ks) {
            const char* xrp = xbc + (strip * 16 + lr) * 256;
            f32x4 xa = *(const f32x4*)(xrp + ((ks * 128 + g * 32)      ^ (lr << 4)));
            f32x4 xb = *(const f32x4*)(xrp + ((ks * 128 + g * 32 + 16) ^ (lr << 4)));
            bf16x8 af;
            af[0] = (__bf16)xa[0]; af[1] = (__bf16)xa[1]; af[2] = (__bf16)xa[2]; af[3] = (__bf16)xa[3];
            af[4] = (__bf16)xb[0]; af[5] = (__bf16)xb[1]; af[6] = (__bf16)xb[2]; af[7] = (__bf16)xb[3];
#pragma unroll
            for (int t = 0; t < 3; ++t) {
                const int nr = (nh * 3 + t) * 16 + lr;
                bf16x8 bf = *(const bf16x8*)(wbc + nr * 128 +
                                             ((ks * 64 + g * 16) ^ rx));
                acc[t] = mfma16(af, bf, acc[t]);
            }
        }
    }

    // ---- epilogue: q/k direct (coalesced-enough, wave-uniform branches)
    const int orow_l = strip * 16 + g * 4;   // m within block, 0..63 (+r)
#pragma unroll
    for (int t = 0; t < 3; ++t) {
        const int n = (nh * 3 + t) * 16 + lr;
        if (n < 128) {
#pragma unroll
            for (int r = 0; r < 4; ++r) {
                const int m = blockIdx.x * 64 + orow_l + r;
                __bf16 hv = (__bf16)acc[t][r];
                if (n < 64) q[(size_t)m * 64 + n] = hv;
                else        k[(size_t)m * 64 + (n - 64)] = hv;
            }
        }
    }

    // ---- vT via LDS transpose. Drain wrap-prefetch (it writes xbuf[0/1]!)
    // then reuse xbuf[0] as vt[64 d][128B m], XOR key (nn&7)<<4 (2-way, free).
    asm volatile("s_waitcnt vmcnt(0) lgkmcnt(0)" ::: "memory");
    __syncthreads();
    char* vt = &xbuf[0][0];   // 8 KiB used
#pragma unroll
    for (int t = 0; t < 3; ++t) {
        const int n = (nh * 3 + t) * 16 + lr;
        if (n >= 128) {
            const int nn  = n - 128;
            const int key = (nn & 7) << 4;
#pragma unroll
            for (int r = 0; r < 4; ++r) {
                const int mm = orow_l + r;
                *(__bf16*)(vt + nn * 128 + ((mm * 2) ^ key)) = (__bf16)acc[t][r];
            }
        }
    }
    __syncthreads();
    // coalesced store: waves 0..7 cover 8 d-rows each (8 lanes x 16B / row).
    // physical slot s of row nn holds logical m-block sl = s ^ (nn&7).
    if (wave < 8) {
        const int nn = wave * 8 + (lane >> 3);
        const int s  = lane & 7;
        const int sl = s ^ (nn & 7);
        bf16x8 vv = *(const bf16x8*)(vt + nn * 128 + s * 16);
        __bf16* dst = vT + (size_t)(blockIdx.x >> 6) * 64 * SEQ
                    + (size_t)nn * SEQ + (blockIdx.x & 63) * 64 + sl * 8;
        *(bf16x8*)dst = vv;
    }
}

// ---------------- k2: flash attention, LDS-staged K/V, 16 waves.
// grid = (SEQ/64, BATCH) = 256 blocks, 1024 threads
// (4 q-strips x 4 kv-parities). Triple-buffered, counted vmcnt(2).
__global__ __launch_bounds__(1024, 4) void attn(
        const __bf16* __restrict__ q, const __bf16* __restrict__ k,
        const __bf16* __restrict__ vT, float* __restrict__ out) {
    const int tid  = threadIdx.x;
    const int wave = tid >> 6, lane = tid & 63;
    const int strip = wave & 3, par = wave >> 2;
    const int b  = blockIdx.y;
    const int q0 = blockIdx.x * 64 + strip * 16;
    const int lr = lane & 15;
    const int g  = lane >> 4;
    const int lk = g * 8;
    const int rx = (lr & 7) << 4;

    const __bf16* qp = q  + (size_t)b * SEQ * 64;
    const __bf16* kp = k  + (size_t)b * SEQ * 64;
    const __bf16* vp = vT + (size_t)b * 64 * SEQ;

    __shared__ __align__(16) char kbuf[3][KVT * 128];   // 48 KiB (128r x 128B)
    __shared__ __align__(16) char vbuf[3][64 * 256];    // 48 KiB (64r x 256B)
    __shared__ __align__(16) char pbuf[16][2048];       // 32 KiB
    char* pw = &pbuf[wave][0];

    const int  srow8 = lane >> 3;                        // K: 8 rows/instr
    const int  sswK  = ((lane & 7) << 4) ^ ((srow8 & 7) << 4);
    const int  vrow  = wave * 4 + (lane >> 4);           // V: 4 rows/instr
    const int  sswV  = ((lane & 15) ^ (vrow & 7)) << 4;

    auto stage = [&](int buf, int kv0) {   // exactly 2 VMEM ops per wave
        gload_lds16((const char*)kp + (size_t)(kv0 + wave * 8 + srow8) * 128 + sswK,
                    &kbuf[buf][wave * 8 * 128]);
        gload_lds16((const char*)vp + (size_t)vrow * (SEQ * 2) +
                        (size_t)kv0 * 2 + sswV,
                    &vbuf[buf][wave * 4 * 256]);
    };

    bf16x8 qf0 = *(const bf16x8*)(qp + (size_t)(q0 + lr) * 64 + lk);
    bf16x8 qf1 = *(const bf16x8*)(qp + (size_t)(q0 + lr) * 64 + 32 + lk);

    f32x4 acc_o[4];
#pragma unroll
    for (int t = 0; t < 4; ++t) acc_o[t] = f32x4{0.f, 0.f, 0.f, 0.f};
    float l_run = 0.f;

    stage(0, 0);
    asm volatile("s_waitcnt vmcnt(0) lgkmcnt(0)" ::: "memory");
    __builtin_amdgcn_s_barrier();

    constexpr int NT = SEQ / KVT;   // 32
    int cur = 0, nxt = 1;
    for (int it = 0; it < NT; ++it) {
        stage(nxt, ((it + 1) & (NT - 1)) * KVT);          // wrap keeps count const
        asm volatile("s_waitcnt vmcnt(2) lgkmcnt(0)" ::: "memory");
        __builtin_amdgcn_s_barrier();

        // ---- S^T = K Q^T on parity's 32 kv rows (exp2 domain)
        f32x4 s4[2];
#pragma unroll
        for (int j = 0; j < 2; ++j) {
            const char* kr = &kbuf[cur][(par * 32 + j * 16 + lr) * 128];
            bf16x8 kf0 = *(const bf16x8*)(kr + ((g * 16) ^ rx));
            bf16x8 kf1 = *(const bf16x8*)(kr + ((64 + g * 16) ^ rx));
            f32x4 a = f32x4{0.f, 0.f, 0.f, 0.f};
            a = mfma16(kf0, qf0, a);
            a = mfma16(kf1, qf1, a);
            s4[j] = a;
        }

        // ---- max-free softmax; pack P (16q x 32kv, swizzled rows of 128B)
#pragma unroll
        for (int j = 0; j < 2; ++j) {
            bf16x4 pbv;
#pragma unroll
            for (int r = 0; r < 4; ++r) {
                float p = __builtin_amdgcn_exp2f(s4[j][r]);
                l_run += p;
                pbv[r] = (__bf16)p;
            }
            *(bf16x4*)(pw + lr * 128 + ((j * 32 + g * 8) ^ rx)) = pbv;
        }
        asm volatile("s_waitcnt lgkmcnt(0)" ::: "memory");

        // ---- O^T += V^T P on parity's kv slice (one 32-wide K-step)
        bf16x8 pf = *(const bf16x8*)(pw + lr * 128 + ((g * 16) ^ rx));
#pragma unroll
        for (int t = 0; t < 4; ++t) {
            const char* vr = &vbuf[cur][(t * 16 + lr) * 256];
            bf16x8 vf = *(const bf16x8*)(vr + ((par * 64 + g * 16) ^ rx));
            acc_o[t] = mfma16(vf, pf, acc_o[t]);
        }

        cur = nxt; nxt = (nxt == 2) ? 0 : nxt + 1;
    }

    // ---- 4-parity merge (plain sums: max-free). kbuf/vbuf dead -> reuse.
    l_run += __shfl_xor(l_run, 16);
    l_run += __shfl_xor(l_run, 32);
    __syncthreads();   // full drain (incl. wrap prefetch) before LDS reuse

    float* mo = (float*)(&kbuf[0][0]);   // [3][4][16][64] f32 = 48 KiB
    float* ml = (float*)(&vbuf[0][0]);   // [3][4][16] f32
    if (par > 0) {
        const int pi = par - 1;
        float* dst = mo + (size_t)((pi * 4 + strip) * 16 + lr) * 64;
#pragma unroll
        for (int t = 0; t < 4; ++t)
            *(f32x4*)(dst + t * 16 + g * 4) = acc_o[t];
        if (lane < 16) ml[(pi * 4 + strip) * 16 + lr] = l_run;
    }
    __syncthreads();
    if (par == 0) {
        float L = l_run;
#pragma unroll
        for (int pi = 0; pi < 3; ++pi) L += ml[(pi * 4 + strip) * 16 + lr];
        float inv = 1.f / L;
        float* ob = out + ((size_t)b * SEQ + q0 + lr) * 64;
#pragma unroll
        for (int t = 0; t < 4; ++t) {
            f32x4 o4 = acc_o[t];
#pragma unroll
            for (int pi = 0; pi < 3; ++pi)
                o4 += *(const f32x4*)(mo + (size_t)((pi * 4 + strip) * 16 + lr) * 64 +
                                      t * 16 + g * 4);
#pragma unroll
            for (int r = 0; r < 4; ++r) o4[r] *= inv;
            *(f32x4*)(ob + t * 16 + g * 4) = o4;
        }
    }
}

extern "C" void kernel_launch(void* const* d_in, const int* in_sizes, int n_in,
                              void* d_out, int out_size, void* d_ws, size_t ws_size,
                              hipStream_t stream) {
    const float* x  = (const float*)d_in[0];
    const float* Wq = (const float*)d_in[1];
    const float* Wk = (const float*)d_in[2];
    const float* Wv = (const float*)d_in[3];
    float* out = (float*)d_out;

    char* ws = (char*)d_ws;
    __bf16* wb = (__bf16*)(ws);
    __bf16* qb = (__bf16*)(ws + 294912);
    __bf16* kb = (__bf16*)(ws + 294912 + 2097152);
    __bf16* vT = (__bf16*)(ws + 294912 + 2u * 2097152);

    convert_w<<<dim3((NTOT * DIN + 255) / 256), dim3(256), 0, stream>>>(Wq, Wk, Wv, wb);
    qkv_proj<<<dim3(MROWS / 64), dim3(1024), 0, stream>>>(x, wb, qb, kb, vT);
    attn<<<dim3(SEQ / 64, BATCH), dim3(1024), 0, stream>>>(qb, kb, vT, out);
}